// Round 4
// baseline (654.335 us; speedup 1.0000x reference)
//
#include <hip/hip_runtime.h>
#include <math.h>

#define H 4096
#define NE 64
#define KTOP 8
#define BT 64
#define TTOT 16384
#define NBLK (TTOT / BT)   // 256
#define KSLC (H / 8)       // 512 K per wave (8 waves per block)
#define TAU 1e-4f
#define DELTA 1e-3f

// 4 reduce slots of [64 tok][64 exp], columns XOR-swizzled -> conflict-free.
union __align__(16) Smem1 {
  float lgs[4 * 64 * 64];                            // 65536 B
  struct { float msum[8][64]; float cnt[8][64]; } ax; // aliases lgs; used after barrier
};
#define LGI(g, t, e) (((g) << 12) + ((t) << 6) + ((e) ^ ((t) & 31)))

// Pass 1: register/SGPR router GEMM (lane=token, s_load for w, no LDS in the
// K-loop) + LDS reduce tree + top-9 + flag/mask + fp32 outputs + aux partials.
__global__ __launch_bounds__(512) void moe_pass1(
    const float* __restrict__ x, const float* __restrict__ wt,
    float* __restrict__ out, unsigned int* __restrict__ wmask,
    float* __restrict__ waux) {
  __shared__ Smem1 sm;
  const int tid = threadIdx.x;
  const int lane = tid & 63;
  const int wid = tid >> 6;
  const int wu = __builtin_amdgcn_readfirstlane(wid);  // uniform wave id
  const int tok0 = blockIdx.x * BT;

  // ---- GEMM: acc[e] per lane over this wave's K-slice ----
  float acc[NE];
#pragma unroll
  for (int e = 0; e < NE; ++e) acc[e] = 0.f;

  const float* xr = x + (size_t)(tok0 + lane) * H + wu * KSLC;
  const float* wb = wt + (size_t)wu * KSLC;

  float4 xa = *(const float4*)(xr);
  float4 xb = *(const float4*)(xr + 4);
#pragma unroll 1
  for (int kk = 0; kk < KSLC; kk += 8) {
    float4 na = xa, nb = xb;
    if (kk + 8 < KSLC) {  // register prefetch: hide HBM latency under 512 FMAs
      na = *(const float4*)(xr + kk + 8);
      nb = *(const float4*)(xr + kk + 12);
    }
#pragma unroll
    for (int e = 0; e < NE; ++e) {
      const float* wr = wb + (size_t)e * H + kk;  // uniform -> s_load_dwordx8
      float a = acc[e];
      a = fmaf(xa.x, wr[0], a);
      a = fmaf(xa.y, wr[1], a);
      a = fmaf(xa.z, wr[2], a);
      a = fmaf(xa.w, wr[3], a);
      a = fmaf(xb.x, wr[4], a);
      a = fmaf(xb.y, wr[5], a);
      a = fmaf(xb.z, wr[6], a);
      a = fmaf(xb.w, wr[7], a);
      acc[e] = a;
    }
    xa = na; xb = nb;
  }

  // ---- reduce 8 wave-partials -> logits in slots 0+1 ----
  if (wid >= 4) {
#pragma unroll
    for (int e = 0; e < NE; ++e) sm.lgs[LGI(wid - 4, lane, e)] = acc[e];
  }
  __syncthreads();
  if (wid < 4) {
#pragma unroll
    for (int e = 0; e < NE; ++e) sm.lgs[LGI(wid, lane, e)] += acc[e];
  }
  __syncthreads();
  if (wid < 2) {
#pragma unroll
    for (int e = 0; e < NE; ++e)
      sm.lgs[LGI(wid, lane, e)] += sm.lgs[LGI(wid + 2, lane, e)];
  }
  __syncthreads();

  // ---- epilogue: 8 waves x 8 tokens, lane = expert ----
  float msum = 0.f;
  int cnt = 0;
#pragma unroll 1
  for (int it = 0; it < 8; ++it) {
    const int t = wid * 8 + it;
    const float lf = sm.lgs[LGI(0, t, lane)] + sm.lgs[LGI(1, t, lane)];

    // fp32 softmax (aux partials)
    float m = lf;
#pragma unroll
    for (int off = 32; off; off >>= 1) m = fmaxf(m, __shfl_xor(m, off));
    float p = expf(lf - m);
    float s = p;
#pragma unroll
    for (int off = 32; off; off >>= 1) s += __shfl_xor(s, off);
    msum += p / s;

    // top-9 by logit, descending, tie -> lowest index
    float cur = lf;
    float myv = 0.f;
    int myi = 0;
#pragma unroll
    for (int r = 0; r < 9; ++r) {
      float v = cur;
      int ix = lane;
#pragma unroll
      for (int off = 1; off < 64; off <<= 1) {
        float ov = __shfl_xor(v, off);
        int oi = __shfl_xor(ix, off);
        if (ov > v || (ov == v && oi < ix)) { v = ov; ix = oi; }
      }
      if (lane == r) { myv = v; myi = ix; }
      if (r < 8 && lane == ix) { cur = -INFINITY; ++cnt; }
    }

    // weights: exp(l - m0) / sum_top8 (full-softmax denominator cancels)
    const float m0 = __shfl(myv, 0);
    float e = expf(myv - m0);
    float sv = e;
    sv += __shfl_xor(sv, 1);
    sv += __shfl_xor(sv, 2);
    sv += __shfl_xor(sv, 4);
    const float wgtv = e / sv;
    const int tg = tok0 + t;
    if (lane < KTOP) {
      out[(size_t)tg * KTOP + lane] = (float)myi;
      out[(size_t)TTOT * KTOP + (size_t)tg * KTOP + lane] = wgtv;
    }

    // ambiguity flag: any adjacent gap among ranks 0..8 below TAU
    const float nxt = __shfl(myv, (lane + 1) & 63);
    const bool gp = (lane < 8) && (myv - nxt < TAU);
    const unsigned long long anyg = __ballot(gp);
    // candidate mask: experts within DELTA of the 8th-largest logit
    const float v7 = __shfl(myv, 7);
    const unsigned long long msk = __ballot(lf >= v7 - DELTA);
    if (lane == 0) {
      const unsigned long long mv = anyg ? msk : 0ULL;
      wmask[tg] = (unsigned)mv;
      wmask[TTOT + tg] = (unsigned)(mv >> 32);
    }
  }
  __syncthreads();  // all lgs reads done; safe to alias with ax
  sm.ax.msum[wid][lane] = msum;
  sm.ax.cnt[wid][lane] = (float)cnt;
  __syncthreads();
  if (tid < 64) {
    float c8 = 0.f, m8 = 0.f;
#pragma unroll
    for (int k = 0; k < 8; ++k) { c8 += sm.ax.cnt[k][tid]; m8 += sm.ax.msum[k][tid]; }
    waux[blockIdx.x * 128 + tid] = c8;
    waux[blockIdx.x * 128 + 64 + tid] = m8;
  }
}

// Pass 2: fp64 recompute of candidate experts for flagged tokens only.
__global__ __launch_bounds__(256) void moe_pass2(
    const float* __restrict__ x, const float* __restrict__ w,
    const unsigned int* __restrict__ wmask, float* __restrict__ out) {
  __shared__ unsigned int slo[64], shi[64];
  __shared__ double red[4];
  __shared__ double cval[64];
  __shared__ int cidx[64];
  const int tid = threadIdx.x;
  const int lane = tid & 63, wid = tid >> 6;
  const int t0 = blockIdx.x * BT;

  if (tid < 64) { slo[tid] = wmask[t0 + tid]; shi[tid] = wmask[TTOT + t0 + tid]; }
  __syncthreads();
  int myf = (tid < 64) ? ((slo[tid] | shi[tid]) != 0u) : 0;
  if (!__syncthreads_or(myf)) return;  // whole block clean

#pragma unroll 1
  for (int tt = 0; tt < BT; ++tt) {
    const unsigned lo = slo[tt], hi = shi[tt];
    if (!(lo | hi)) continue;  // uniform branch
    const int t = t0 + tt;
    const unsigned long long m = ((unsigned long long)hi << 32) | lo;
    const float* xr = x + (size_t)t * H;
    int ncand = 0;
#pragma unroll 1
    for (int e = 0; e < 64; ++e) {
      if (!((m >> e) & 1ULL)) continue;  // uniform
      const float* wr = w + (size_t)e * H;
      double d = 0.0;
#pragma unroll
      for (int q = 0; q < 16; ++q) {
        const int k = tid + 256 * q;
        d = fma((double)xr[k], (double)wr[k], d);
      }
#pragma unroll
      for (int off = 32; off; off >>= 1) d += __shfl_xor(d, off);
      if (lane == 0) red[wid] = d;
      __syncthreads();
      if (tid == 0) {
        cval[ncand] = red[0] + red[1] + red[2] + red[3];
        cidx[ncand] = e;
      }
      __syncthreads();
      ++ncand;
    }
    if (tid == 0) {
      double sel[8];
      int si[8];
      for (int r = 0; r < 8; ++r) {
        int best = 0;
        double bv = -1e300;
        for (int c2 = 0; c2 < ncand; ++c2)
          if (cval[c2] > bv) { bv = cval[c2]; best = c2; }  // tie -> lowest e
        sel[r] = cval[best]; si[r] = cidx[best];
        cval[best] = -1e301;
      }
      const double m0 = sel[0];
      float es[8], ssum = 0.f;
      for (int r = 0; r < 8; ++r) { es[r] = expf((float)(sel[r] - m0)); ssum += es[r]; }
      for (int r = 0; r < 8; ++r) {
        out[(size_t)t * KTOP + r] = (float)si[r];
        out[(size_t)TTOT * KTOP + (size_t)t * KTOP + r] = es[r] / ssum;
      }
    }
    __syncthreads();
  }
}

// aux = alpha * mean_b sum_e (count[b,e]/(S*K/E)) * (scoresum[b,e]/S)
__global__ __launch_bounds__(256) void moe_gate_aux(
    const float* __restrict__ waux, float* __restrict__ out) {
  const int tid = threadIdx.x;
  const int b = tid >> 6, e = tid & 63;
  float cnt = 0.f, ms = 0.f;
#pragma unroll 4
  for (int j = 0; j < 64; ++j) {
    const int blk = b * 64 + j;
    cnt += waux[blk * 128 + e];
    ms += waux[blk * 128 + 64 + e];
  }
  float term = (cnt * (1.f / 512.f)) * (ms * (1.f / 4096.f));
  __shared__ float red[4];
#pragma unroll
  for (int off = 32; off; off >>= 1) term += __shfl_xor(term, off);
  if ((tid & 63) == 0) red[tid >> 6] = term;
  __syncthreads();
  if (tid == 0) {
    float tot = red[0] + red[1] + red[2] + red[3];
    out[(size_t)TTOT * KTOP * 2] = tot * (0.001f / 4.f);
  }
}

extern "C" void kernel_launch(void* const* d_in, const int* in_sizes, int n_in,
                              void* d_out, int out_size, void* d_ws, size_t ws_size,
                              hipStream_t stream) {
  (void)in_sizes; (void)n_in; (void)out_size; (void)ws_size;
  const float* x = (const float*)d_in[0];
  const float* w = (const float*)d_in[1];
  float* out = (float*)d_out;
  unsigned int* wmask = (unsigned int*)d_ws;                      // 2*TTOT u32 = 128 KB
  float* waux = (float*)((char*)d_ws + (size_t)2 * TTOT * 4);     // NBLK*128 f32 = 128 KB
  moe_pass1<<<NBLK, 512, 0, stream>>>(x, w, out, wmask, waux);
  moe_pass2<<<NBLK, 256, 0, stream>>>(x, w, wmask, out);
  moe_gate_aux<<<1, 256, 0, stream>>>(waux, out);
}

// Round 5
// 204.793 us; speedup vs baseline: 3.1951x; 3.1951x over previous
//
#include <hip/hip_runtime.h>
#include <math.h>

#define H 4096
#define NE 64
#define KTOP 8
#define BT 64
#define TTOT 16384
#define NBLK (TTOT / BT)        // 256
#define TAU 1e-4f
#define DELTA 1e-3f

typedef __attribute__((ext_vector_type(8))) short bf16x8;
typedef __attribute__((ext_vector_type(4))) float f32x4;

union U4S8 { uint4 u; bf16x8 s; };

__device__ __forceinline__ unsigned bf16_rne(float f) {
  unsigned b = __float_as_uint(f);
  b += 0x7fffu + ((b >> 16) & 1u);
  return b >> 16;
}

// Convert w fp32 -> hi/lo bf16, pre-swizzled per-32k-chunk images.
// Image for chunk c: 256 uint4; uint4 index = e*4 + (s ^ ((e>>1)&3)),
// holding w[e][c*32 + s*8 .. +7]. hi array = images 0..127, lo = next 128.
__global__ __launch_bounds__(256) void w_prep(const float* __restrict__ w,
                                              uint4* __restrict__ wsimg) {
  const int sid = blockIdx.x * 256 + threadIdx.x;   // 0..32767
  const int e = sid >> 9;
  const int rem = sid & 511;
  const int c = rem >> 2;
  const int s = rem & 3;
  const float* src = w + (size_t)e * H + c * 32 + s * 8;
  float4 f0 = *(const float4*)src;
  float4 f1 = *(const float4*)(src + 4);
  float xf[8] = {f0.x, f0.y, f0.z, f0.w, f1.x, f1.y, f1.z, f1.w};
  unsigned hu[8], lu[8];
#pragma unroll
  for (int j = 0; j < 8; ++j) {
    hu[j] = bf16_rne(xf[j]);
    float hf = __uint_as_float(hu[j] << 16);
    lu[j] = bf16_rne(xf[j] - hf);
  }
  uint4 hp, lp;
  hp.x = hu[0] | (hu[1] << 16); hp.y = hu[2] | (hu[3] << 16);
  hp.z = hu[4] | (hu[5] << 16); hp.w = hu[6] | (hu[7] << 16);
  lp.x = lu[0] | (lu[1] << 16); lp.y = lu[2] | (lu[3] << 16);
  lp.z = lu[4] | (lu[5] << 16); lp.w = lu[6] | (lu[7] << 16);
  const int slotp = s ^ ((e >> 1) & 3);
  wsimg[(size_t)c * 256 + e * 4 + slotp] = hp;
  wsimg[(size_t)128 * 256 + (size_t)c * 256 + e * 4 + slotp] = lp;
}

struct __align__(16) SmemP1 {
  uint4 wbuf[2][1024];     // 32 KB: [buf][(kh*2+hl)*256 + e*4 + slotp]
  float lg[64 * 66];       // logits, padded stride
  float msum[8][64];
  float cnt[8][64];
};

// Pass 1: bf16-split MFMA router GEMM + top-9 + flag/mask + outputs + aux.
__global__ __launch_bounds__(512) void moe_pass1(
    const float* __restrict__ x, const uint4* __restrict__ wsimg,
    float* __restrict__ out, unsigned* __restrict__ wmask,
    float* __restrict__ waux) {
  __shared__ SmemP1 sm;
  const int tid = threadIdx.x;
  const int lane = tid & 63;
  const int wid = tid >> 6;
  const int tile = wid & 3;            // token tile 0..3 (16 tokens)
  const int kh = wid >> 2;             // K-half 0..1 (2048 each)
  const int tok0 = blockIdx.x * BT;
  const int trow = lane & 15;
  const int kgrp = lane >> 4;

  // staging role: 512 thr cover 16 KB = 4 images (2 half x hi/lo)
  const int sh = tid >> 8;
  const int shl = (tid >> 7) & 1;
  const int sfl = tid & 127;
  const uint4* simg = wsimg + (size_t)shl * (128 * 256);
  const int sdst = (sh * 2 + shl) * 256 + sfl * 2;

  // x in exact A-frag layout: lane reads 8 contiguous k
  const float* xp = x + (size_t)(tok0 + tile * 16 + trow) * H + kh * 2048 + kgrp * 8;

  // B-frag LDS uint4 indices
  int bidx[2][4];
#pragma unroll
  for (int hl = 0; hl < 2; ++hl)
#pragma unroll
    for (int et = 0; et < 4; ++et) {
      int e = et * 16 + trow;
      bidx[hl][et] = (kh * 2 + hl) * 256 + e * 4 + (kgrp ^ ((e >> 1) & 3));
    }

  f32x4 acc[4];
#pragma unroll
  for (int et = 0; et < 4; ++et) acc[et] = (f32x4){0.f, 0.f, 0.f, 0.f};

  // prologue: stage chunk 0, preload x(0)
  {
    const int cg = sh ? 64 : 0;
    uint4 a = simg[(size_t)cg * 256 + sfl * 2];
    uint4 b = simg[(size_t)cg * 256 + sfl * 2 + 1];
    sm.wbuf[0][sdst] = a;
    sm.wbuf[0][sdst + 1] = b;
  }
  float4 xc0 = *(const float4*)(xp);
  float4 xc1 = *(const float4*)(xp + 4);
  __syncthreads();

#pragma unroll 1
  for (int c = 0; c < 64; ++c) {
    uint4 wg0, wg1;
    float4 xn0, xn1;
    const bool more = (c + 1) < 64;
    if (more) {  // issue next-chunk loads early (HBM latency hides under compute)
      const int cg = (sh ? 64 : 0) + c + 1;
      wg0 = simg[(size_t)cg * 256 + sfl * 2];
      wg1 = simg[(size_t)cg * 256 + sfl * 2 + 1];
      xn0 = *(const float4*)(xp + (c + 1) * 32);
      xn1 = *(const float4*)(xp + (c + 1) * 32 + 4);
    }
    const int buf = c & 1;
    // B-frags (hi/lo x 4 expert tiles)
    U4S8 bh[4], bl[4];
#pragma unroll
    for (int et = 0; et < 4; ++et) {
      bh[et].u = sm.wbuf[buf][bidx[0][et]];
      bl[et].u = sm.wbuf[buf][bidx[1][et]];
    }
    // A-frags: split x into bf16 hi/lo via packed cvt
    float xf[8] = {xc0.x, xc0.y, xc0.z, xc0.w, xc1.x, xc1.y, xc1.z, xc1.w};
    unsigned ph[4], pl[4];
#pragma unroll
    for (int q = 0; q < 4; ++q)
      asm("v_cvt_pk_bf16_f32 %0, %1, %2" : "=v"(ph[q]) : "v"(xf[2 * q]), "v"(xf[2 * q + 1]));
    float rs[8];
#pragma unroll
    for (int q = 0; q < 4; ++q) {
      rs[2 * q]     = xf[2 * q]     - __uint_as_float(ph[q] << 16);
      rs[2 * q + 1] = xf[2 * q + 1] - __uint_as_float(ph[q] & 0xffff0000u);
    }
#pragma unroll
    for (int q = 0; q < 4; ++q)
      asm("v_cvt_pk_bf16_f32 %0, %1, %2" : "=v"(pl[q]) : "v"(rs[2 * q]), "v"(rs[2 * q + 1]));
    U4S8 ah, al;
    ah.u = (uint4){ph[0], ph[1], ph[2], ph[3]};
    al.u = (uint4){pl[0], pl[1], pl[2], pl[3]};
    // xh*wh + xh*wl + xl*wh
#pragma unroll
    for (int et = 0; et < 4; ++et) {
      acc[et] = __builtin_amdgcn_mfma_f32_16x16x32_bf16(ah.s, bh[et].s, acc[et], 0, 0, 0);
      acc[et] = __builtin_amdgcn_mfma_f32_16x16x32_bf16(ah.s, bl[et].s, acc[et], 0, 0, 0);
      acc[et] = __builtin_amdgcn_mfma_f32_16x16x32_bf16(al.s, bh[et].s, acc[et], 0, 0, 0);
    }
    if (more) {
      sm.wbuf[buf ^ 1][sdst] = wg0;      // compiler inserts the vmcnt
      sm.wbuf[buf ^ 1][sdst + 1] = wg1;
      xc0 = xn0; xc1 = xn1;
    }
    __syncthreads();
  }

  // cross-half reduce: C[row=(lane>>4)*4+r][col=lane&15] per e-tile
  if (kh == 1) {
#pragma unroll
    for (int et = 0; et < 4; ++et)
#pragma unroll
      for (int r = 0; r < 4; ++r)
        sm.lg[(tile * 16 + kgrp * 4 + r) * 66 + et * 16 + trow] = acc[et][r];
  }
  __syncthreads();
  if (kh == 0) {
#pragma unroll
    for (int et = 0; et < 4; ++et)
#pragma unroll
      for (int r = 0; r < 4; ++r) {
        const int li = (tile * 16 + kgrp * 4 + r) * 66 + et * 16 + trow;
        sm.lg[li] += acc[et][r];
      }
  }
  __syncthreads();

  // epilogue: 8 waves x 8 tokens, lane = expert (round-3/4 proven)
  float msum = 0.f;
  int cnt = 0;
#pragma unroll 1
  for (int it = 0; it < 8; ++it) {
    const int t = wid * 8 + it;
    const float lf = sm.lg[t * 66 + lane];

    float m = lf;
#pragma unroll
    for (int off = 32; off; off >>= 1) m = fmaxf(m, __shfl_xor(m, off));
    float p = expf(lf - m);
    float s = p;
#pragma unroll
    for (int off = 32; off; off >>= 1) s += __shfl_xor(s, off);
    msum += p / s;

    // top-9 by logit, descending, tie -> lowest index
    float cur = lf;
    float myv = 0.f;
    int myi = 0;
#pragma unroll
    for (int r = 0; r < 9; ++r) {
      float v = cur;
      int ix = lane;
#pragma unroll
      for (int off = 1; off < 64; off <<= 1) {
        float ov = __shfl_xor(v, off);
        int oi = __shfl_xor(ix, off);
        if (ov > v || (ov == v && oi < ix)) { v = ov; ix = oi; }
      }
      if (lane == r) { myv = v; myi = ix; }
      if (r < 8 && lane == ix) { cur = -INFINITY; ++cnt; }
    }

    const float m0 = __shfl(myv, 0);
    float e = expf(myv - m0);
    float sv = e;
    sv += __shfl_xor(sv, 1);
    sv += __shfl_xor(sv, 2);
    sv += __shfl_xor(sv, 4);
    const float wgtv = e / sv;
    const int tg = tok0 + t;
    if (lane < KTOP) {
      out[(size_t)tg * KTOP + lane] = (float)myi;
      out[(size_t)TTOT * KTOP + (size_t)tg * KTOP + lane] = wgtv;
    }

    const float nxt = __shfl(myv, (lane + 1) & 63);
    const bool gp = (lane < 8) && (myv - nxt < TAU);
    const unsigned long long anyg = __ballot(gp);
    const float v7 = __shfl(myv, 7);
    const unsigned long long msk = __ballot(lf >= v7 - DELTA);
    if (lane == 0) {
      const unsigned long long mv = anyg ? msk : 0ULL;
      wmask[tg] = (unsigned)mv;
      wmask[TTOT + tg] = (unsigned)(mv >> 32);
    }
  }
  sm.msum[wid][lane] = msum;
  sm.cnt[wid][lane] = (float)cnt;
  __syncthreads();
  if (tid < 64) {
    float c8 = 0.f, m8 = 0.f;
#pragma unroll
    for (int k = 0; k < 8; ++k) { c8 += sm.cnt[k][tid]; m8 += sm.msum[k][tid]; }
    waux[blockIdx.x * 128 + tid] = c8;
    waux[blockIdx.x * 128 + 64 + tid] = m8;
  }
}

// Pass 2: fp64 recompute of candidate experts for flagged tokens only.
__global__ __launch_bounds__(256) void moe_pass2(
    const float* __restrict__ x, const float* __restrict__ w,
    const unsigned* __restrict__ wmask, float* __restrict__ out) {
  __shared__ unsigned slo[64], shi[64];
  __shared__ double red[4];
  __shared__ double cval[64];
  __shared__ int cidx[64];
  const int tid = threadIdx.x;
  const int lane = tid & 63, wid = tid >> 6;
  const int t0 = blockIdx.x * BT;

  if (tid < 64) { slo[tid] = wmask[t0 + tid]; shi[tid] = wmask[TTOT + t0 + tid]; }
  __syncthreads();
  int myf = (tid < 64) ? ((slo[tid] | shi[tid]) != 0u) : 0;
  if (!__syncthreads_or(myf)) return;

#pragma unroll 1
  for (int tt = 0; tt < BT; ++tt) {
    const unsigned lo = slo[tt], hi = shi[tt];
    if (!(lo | hi)) continue;
    const int t = t0 + tt;
    const unsigned long long m = ((unsigned long long)hi << 32) | lo;
    const float* xr = x + (size_t)t * H;
    int ncand = 0;
#pragma unroll 1
    for (int e = 0; e < 64; ++e) {
      if (!((m >> e) & 1ULL)) continue;
      const float* wr = w + (size_t)e * H;
      double d = 0.0;
#pragma unroll
      for (int q = 0; q < 16; ++q) {
        const int k = tid + 256 * q;
        d = fma((double)xr[k], (double)wr[k], d);
      }
#pragma unroll
      for (int off = 32; off; off >>= 1) d += __shfl_xor(d, off);
      if (lane == 0) red[wid] = d;
      __syncthreads();
      if (tid == 0) {
        cval[ncand] = red[0] + red[1] + red[2] + red[3];
        cidx[ncand] = e;
      }
      __syncthreads();
      ++ncand;
    }
    if (tid == 0) {
      double sel[8];
      int si[8];
      for (int r = 0; r < 8; ++r) {
        int best = 0;
        double bv = -1e300;
        for (int c2 = 0; c2 < ncand; ++c2)
          if (cval[c2] > bv) { bv = cval[c2]; best = c2; }
        sel[r] = cval[best]; si[r] = cidx[best];
        cval[best] = -1e301;
      }
      const double m0 = sel[0];
      float es[8], ssum = 0.f;
      for (int r = 0; r < 8; ++r) { es[r] = expf((float)(sel[r] - m0)); ssum += es[r]; }
      for (int r = 0; r < 8; ++r) {
        out[(size_t)t * KTOP + r] = (float)si[r];
        out[(size_t)TTOT * KTOP + (size_t)t * KTOP + r] = es[r] / ssum;
      }
    }
    __syncthreads();
  }
}

// aux = alpha * mean_b sum_e (count[b,e]/(S*K/E)) * (scoresum[b,e]/S)
__global__ __launch_bounds__(256) void moe_gate_aux(
    const float* __restrict__ waux, float* __restrict__ out) {
  const int tid = threadIdx.x;
  const int b = tid >> 6, e = tid & 63;
  float cnt = 0.f, ms = 0.f;
#pragma unroll 4
  for (int j = 0; j < 64; ++j) {
    const int blk = b * 64 + j;
    cnt += waux[blk * 128 + e];
    ms += waux[blk * 128 + 64 + e];
  }
  float term = (cnt * (1.f / 512.f)) * (ms * (1.f / 4096.f));
  __shared__ float red[4];
#pragma unroll
  for (int off = 32; off; off >>= 1) term += __shfl_xor(term, off);
  if ((tid & 63) == 0) red[tid >> 6] = term;
  __syncthreads();
  if (tid == 0) {
    float tot = red[0] + red[1] + red[2] + red[3];
    out[(size_t)TTOT * KTOP * 2] = tot * (0.001f / 4.f);
  }
}

extern "C" void kernel_launch(void* const* d_in, const int* in_sizes, int n_in,
                              void* d_out, int out_size, void* d_ws, size_t ws_size,
                              hipStream_t stream) {
  (void)in_sizes; (void)n_in; (void)out_size; (void)ws_size;
  const float* x = (const float*)d_in[0];
  const float* w = (const float*)d_in[1];
  float* out = (float*)d_out;
  uint4* wsimg = (uint4*)d_ws;                                   // 1 MB hi+lo images
  unsigned* wmask = (unsigned*)((char*)d_ws + (1 << 20));        // 128 KB
  float* waux = (float*)((char*)d_ws + (1 << 20) + 2 * TTOT * 4);// 128 KB
  w_prep<<<128, 256, 0, stream>>>(w, wsimg);
  moe_pass1<<<NBLK, 512, 0, stream>>>(x, wsimg, out, wmask, waux);
  moe_pass2<<<NBLK, 256, 0, stream>>>(x, w, wmask, out);
  moe_gate_aux<<<1, 256, 0, stream>>>(waux, out);
}